// Round 5
// baseline (196.588 us; speedup 1.0000x reference)
//
#include <hip/hip_runtime.h>
#include <math.h>

#define BATCH 1024
#define DIM   256
#define NCL   50000
#define TOTC  100000   // 2*NC
#define NSLICE 16

typedef __attribute__((ext_vector_type(8)))  short bf16x8;   // 8 bf16 = 4 VGPR
typedef __attribute__((ext_vector_type(16))) float f32x16;   // 32x32 acc frag

__device__ __forceinline__ unsigned short f2bf(float f) {   // RNE f32 -> bf16
    unsigned int u = __float_as_uint(f);
    return (unsigned short)((u + 0x7FFFu + ((u >> 16) & 1u)) >> 16);
}

// ---------------------------------------------------------------------------
// Kernel 1: normalize rows -> bf16 xn (LINEAR row-major; k_main reads it
// directly from L2); target logits (f32); zero sliced accumulators.
// One wave per batch row.
// ---------------------------------------------------------------------------
__global__ __launch_bounds__(64) void k_prep(const float* __restrict__ in,
                                             const int* __restrict__ tgt,
                                             const float* __restrict__ feats,
                                             unsigned short* __restrict__ xnb,
                                             float* __restrict__ Sx,
                                             float* __restrict__ z) {
    const int b = blockIdx.x;
    const int t = threadIdx.x;           // 0..63, 4 floats each
    float4 v = *(const float4*)&in[b * DIM + t * 4];
    float ss = v.x * v.x + v.y * v.y + v.z * v.z + v.w * v.w;
#pragma unroll
    for (int o = 1; o < 64; o <<= 1) ss += __shfl_xor(ss, o, 64);
    const float sc = 1.0f / sqrtf(ss);
    float4 w;
    w.x = v.x * sc; w.y = v.y * sc; w.z = v.z * sc; w.w = v.w * sc;

    ushort4 hb;
    hb.x = f2bf(w.x); hb.y = f2bf(w.y); hb.z = f2bf(w.z); hb.w = f2bf(w.w);
    *(ushort4*)&xnb[b * DIM + t * 4] = hb;

    const int tb = tgt[b];
#pragma unroll
    for (int h = 0; h < 2; ++h) {
        const int row = tb + h * NCL;    // mean half rows [0,NC), hard [NC,2NC)
        float4 f = *(const float4*)&feats[row * DIM + t * 4];
        float d = w.x * f.x + w.y * f.y + w.z * f.z + w.w * f.w;
#pragma unroll
        for (int o = 1; o < 64; o <<= 1) d += __shfl_xor(d, o, 64);
        if (t == 0) z[b * 2 + h] = d * 20.0f;
    }
    // zero sliced accumulators: 16*1024*2 = 32768 floats over 1024 blocks
    if (t < 32) Sx[b * 32 + t] = 0.0f;
}

// ---------------------------------------------------------------------------
// Kernel 2: MFMA GEMM + fused sumexp. NO LDS, NO barriers, NO mid-kernel
// atomic waits. 782 blocks x 8 waves; block owns 128 clusters. Each wave
// caches its 64 cluster rows (f32 -> bf16) as MFMA A-frags in 128 VGPRs.
// B-fragments are read directly from the L2-resident xnb (512 KB) per
// K-step. Per-bt sums accumulate in statically-indexed registers; the
// 8 atomics per lane-group fire once at kernel end.
// ---------------------------------------------------------------------------
__global__ __launch_bounds__(512) void k_main(const unsigned short* __restrict__ xnb,
                                              const float* __restrict__ feats,
                                              float* __restrict__ Sx) {
    const int tid  = threadIdx.x;
    const int lane = tid & 63;
    const int wid  = tid >> 6;        // 0..7
    const int wm   = wid >> 2;        // 0..1  (M offset wm*64)
    const int wn   = wid & 3;         // 0..3  (N offset wn*32)
    const int l31  = lane & 31;
    const int hi   = lane >> 5;       // 0/1
    const int cb0  = blockIdx.x * 128;
    float* Ss = Sx + (blockIdx.x & (NSLICE - 1)) * (BATCH * 2);

    // ---- A cache: 2 M-frags x 16 K-steps; lane holds row (base+l31),
    //      k = kk*16 + hi*8 + j ----
    bf16x8 ac[2][16];
#pragma unroll
    for (int mt = 0; mt < 2; ++mt) {
        int row = cb0 + wm * 64 + mt * 32 + l31;
        if (row > TOTC - 1) row = TOTC - 1;        // clamp; masked in epilogue
        const float* rp = &feats[(size_t)row * DIM];
#pragma unroll
        for (int kk = 0; kk < 16; ++kk) {
            const float4 f0 = *(const float4*)&rp[kk * 16 + hi * 8];
            const float4 f1 = *(const float4*)&rp[kk * 16 + hi * 8 + 4];
            bf16x8 a;
            a[0] = (short)f2bf(f0.x); a[1] = (short)f2bf(f0.y);
            a[2] = (short)f2bf(f0.z); a[3] = (short)f2bf(f0.w);
            a[4] = (short)f2bf(f1.x); a[5] = (short)f2bf(f1.y);
            a[6] = (short)f2bf(f1.z); a[7] = (short)f2bf(f1.w);
            ac[mt][kk] = a;
        }
    }

    const bool mixed = (cb0 < NCL && cb0 + 127 >= NCL) || (cb0 + 127 >= TOTC);
    const int  halfsel = (cb0 >= NCL) ? 1 : 0;

    float sreg0[8], sreg1[8];

#pragma unroll
    for (int bt = 0; bt < 8; ++bt) {
        // per-wave B base: batch row bt*128 + wn*32 + l31, bf16 k = hi*8
        const unsigned short* bp = xnb + (size_t)(bt * 128 + wn * 32 + l31) * DIM + hi * 8;

        f32x16 acc0 = (f32x16)(0.0f), acc1 = (f32x16)(0.0f);
#pragma unroll
        for (int kk = 0; kk < 16; ++kk) {
            const bf16x8 bf = *(const bf16x8*)(bp + kk * 16);
            acc0 = __builtin_amdgcn_mfma_f32_32x32x16_bf16(ac[0][kk], bf, acc0, 0, 0, 0);
            acc1 = __builtin_amdgcn_mfma_f32_32x32x16_bf16(ac[1][kk], bf, acc1, 0, 0, 0);
        }

        // ---- epilogue: e = exp(20*d - 20); sum over this wave's 64 clusters
        if (!mixed) {
            float s = 0.0f;
#pragma unroll
            for (int r = 0; r < 16; ++r) {
                s += __expf(fmaf(acc0[r], 20.0f, -20.0f));
                s += __expf(fmaf(acc1[r], 20.0f, -20.0f));
            }
            s += __shfl_xor(s, 32, 64);
            sreg0[bt] = s;
            sreg1[bt] = 0.0f;
        } else {
            float sh0 = 0.0f, sh1 = 0.0f;
#pragma unroll
            for (int mt = 0; mt < 2; ++mt)
#pragma unroll
                for (int r = 0; r < 16; ++r) {
                    const int cl = cb0 + wm * 64 + mt * 32 +
                                   (r & 3) + 8 * (r >> 2) + 4 * hi;
                    const bool valid = cl < TOTC;
                    float e = __expf(fmaf((mt ? acc1[r] : acc0[r]), 20.0f, -20.0f));
                    e = valid ? e : 0.0f;
                    sh0 += (cl < NCL) ? e : 0.0f;
                    sh1 += (cl < NCL) ? 0.0f : e;
                }
            sh0 += __shfl_xor(sh0, 32, 64);
            sh1 += __shfl_xor(sh1, 32, 64);
            sreg0[bt] = sh0;
            sreg1[bt] = sh1;
        }
    }

    // ---- all atomics at the very end: fire-and-forget, off critical path ----
    if (hi == 0) {
        if (!mixed) {
#pragma unroll
            for (int bt = 0; bt < 8; ++bt) {
                const int bcol = bt * 128 + wn * 32 + l31;
                atomicAdd(&Ss[bcol * 2 + halfsel], sreg0[bt]);
            }
        } else {
#pragma unroll
            for (int bt = 0; bt < 8; ++bt) {
                const int bcol = bt * 128 + wn * 32 + l31;
                atomicAdd(&Ss[bcol * 2 + 0], sreg0[bt]);
                atomicAdd(&Ss[bcol * 2 + 1], sreg1[bt]);
            }
        }
    }
}

// ---------------------------------------------------------------------------
// Kernel 3: loss = 0.5 * mean_b[(20+log S0 - z0) + (20+log S1 - z1)],
// summing the 16 slices first.
// ---------------------------------------------------------------------------
__global__ __launch_bounds__(256) void k_loss(const float* __restrict__ Sx,
                                              const float* __restrict__ z,
                                              float* __restrict__ out) {
    const int t = threadIdx.x;
    float part = 0.0f;
    for (int r = t; r < BATCH; r += 256) {
        float s0 = 0.0f, s1 = 0.0f;
#pragma unroll
        for (int sl = 0; sl < NSLICE; ++sl) {
            s0 += Sx[sl * (BATCH * 2) + r * 2 + 0];
            s1 += Sx[sl * (BATCH * 2) + r * 2 + 1];
        }
        part += 40.0f + logf(s0) + logf(s1) - z[r * 2 + 0] - z[r * 2 + 1];
    }
#pragma unroll
    for (int o = 1; o < 64; o <<= 1) part += __shfl_xor(part, o, 64);
    __shared__ float ws[4];
    if ((t & 63) == 0) ws[t >> 6] = part;
    __syncthreads();
    if (t == 0) {
        const float tot = ws[0] + ws[1] + ws[2] + ws[3];
        out[0] = 0.5f * tot / (float)BATCH;
    }
}

// ---------------------------------------------------------------------------
extern "C" void kernel_launch(void* const* d_in, const int* in_sizes, int n_in,
                              void* d_out, int out_size, void* d_ws, size_t ws_size,
                              hipStream_t stream) {
    const float* inputs  = (const float*)d_in[0];
    const int*   targets = (const int*)d_in[1];
    const float* feats   = (const float*)d_in[2];
    float* out = (float*)d_out;

    unsigned short* xnb = (unsigned short*)d_ws;          // 1024*256 bf16 = 512 KB
    float* Sx = (float*)(xnb + BATCH * DIM);              // 16*1024*2 f32 = 128 KB
    float* zt = Sx + NSLICE * BATCH * 2;                  // 1024*2 f32

    k_prep<<<BATCH, 64, 0, stream>>>(inputs, targets, feats, xnb, Sx, zt);
    const int nblk = (TOTC + 127) / 128;                  // 782
    k_main<<<nblk, 512, 0, stream>>>(xnb, feats, Sx);
    k_loss<<<1, 256, 0, stream>>>(Sx, zt, out);
}